// Round 3
// baseline (496.628 us; speedup 1.0000x reference)
//
#include <hip/hip_runtime.h>
#include <hip/hip_bf16.h>

typedef __bf16 bf16_t;
typedef __bf16 bf16x8 __attribute__((ext_vector_type(8)));
typedef float  f32x4  __attribute__((ext_vector_type(4)));

#define CIN  64
#define COUT 128
#define HH   224
#define WW   224
#define OH   222
#define OW   222
#define XT_RS 72   // padded ci-stride (144 B rows -> lanes spread over banks)

// -------- prepack: wpk[off][co][ci] = bf16(w[co][ci][kh][kw]), off = kh*3+kw
__global__ void prepack_w(const float* __restrict__ w, bf16_t* __restrict__ wpk) {
    int idx = blockIdx.x * 256 + threadIdx.x;
    if (idx >= 9 * COUT * CIN) return;
    int ci  = idx & 63;
    int co  = (idx >> 6) & 127;
    int off = idx >> 13;               // 128*64 = 8192 = 2^13
    wpk[idx] = (bf16_t)w[(co * CIN + ci) * 9 + off];
}

// -------- main: implicit-GEMM conv + bias + channel-min + tanh(tanh)
__global__ __launch_bounds__(256) void conv_min_tanh(
    const float* __restrict__ x, const float* __restrict__ w,
    const float* __restrict__ bias, const bf16_t* __restrict__ wpk,
    float* __restrict__ out)
{
    __shared__ __align__(16) bf16_t xt[10 * 18 * XT_RS];  // 25,920 B
    __shared__ __align__(16) bf16_t wl[COUT * XT_RS];     // 18,432 B
    __shared__ float red[2][8][16];                        // 1 KB

    const int tid = threadIdx.x;
    const int lane = tid & 63;
    const int wv  = tid >> 6;
    const int wgM = wv >> 1;        // pixel-row group: rows 0-3 / 4-7
    const int wgN = wv & 1;         // co group: 0-63 / 64-127
    const int l15 = lane & 15;
    const int lg  = lane >> 4;      // k-group / D-row group

    const int owb = blockIdx.x * 16;
    const int ohb = blockIdx.y * 8;
    const int b   = blockIdx.z;

    // ---- stage x tile (fp32 -> bf16), rows ohb..ohb+9, cols owb..owb+17, all 64 ci
    const float* xb = x + (size_t)b * (CIN * HH * WW);
    for (int idx = tid; idx < 10 * 18 * CIN; idx += 256) {
        int c  = idx % 18;
        int r  = (idx / 18) % 10;
        int ci = idx / 180;
        int rg = ohb + r; if (rg > HH - 1) rg = HH - 1;   // clamp: clamped data only
        int cg = owb + c; if (cg > WW - 1) cg = WW - 1;   // feeds discarded outputs
        xt[(r * 18 + c) * XT_RS + ci] = (bf16_t)xb[(ci * HH + rg) * WW + cg];
    }

    // ---- per-lane bias for the 4 N-frags
    float bias4[4];
#pragma unroll
    for (int ni = 0; ni < 4; ni++) bias4[ni] = bias[wgN * 64 + ni * 16 + l15];

    f32x4 acc[4][4];
#pragma unroll
    for (int mi = 0; mi < 4; mi++)
#pragma unroll
        for (int ni = 0; ni < 4; ni++)
            acc[mi][ni] = (f32x4){0.f, 0.f, 0.f, 0.f};

    // ---- K loop: 9 taps (kh,kw), each 64 ci = 2 MFMA K-steps of 32
#pragma unroll
    for (int off = 0; off < 9; off++) {
        __syncthreads();   // xt ready (off=0) / wl readers done (off>0)
        {
            const int co = tid >> 1, half = tid & 1;
            if (wpk) {     // bf16 prepacked path: 64 B contiguous per thread
                const uint4* src = reinterpret_cast<const uint4*>(
                    wpk + (size_t)(off * COUT + co) * CIN + half * 32);
                uint4 v0 = src[0], v1 = src[1], v2 = src[2], v3 = src[3];
                uint4* dst = reinterpret_cast<uint4*>(&wl[co * XT_RS + half * 32]);
                dst[0] = v0; dst[1] = v1; dst[2] = v2; dst[3] = v3;
            } else {       // fallback: gather fp32 weights (stride 36 B), convert
#pragma unroll
                for (int j = 0; j < 32; j++) {
                    int ci = half * 32 + j;
                    wl[co * XT_RS + ci] = (bf16_t)w[(co * CIN + ci) * 9 + off];
                }
            }
        }
        __syncthreads();

        const int kh = off / 3, kw = off % 3;
#pragma unroll
        for (int kk = 0; kk < 2; kk++) {
            bf16x8 af[4], bfr[4];
#pragma unroll
            for (int mi = 0; mi < 4; mi++) {
                int row = wgM * 4 + mi + kh;       // input row in tile
                int col = l15 + kw;                // input col in tile (m-index = l15)
                af[mi] = *reinterpret_cast<const bf16x8*>(
                    &xt[(row * 18 + col) * XT_RS + kk * 32 + lg * 8]);
            }
#pragma unroll
            for (int ni = 0; ni < 4; ni++) {
                int co = wgN * 64 + ni * 16 + l15;
                bfr[ni] = *reinterpret_cast<const bf16x8*>(
                    &wl[co * XT_RS + kk * 32 + lg * 8]);
            }
#pragma unroll
            for (int mi = 0; mi < 4; mi++)
#pragma unroll
                for (int ni = 0; ni < 4; ni++)
                    acc[mi][ni] = __builtin_amdgcn_mfma_f32_16x16x32_bf16(
                        af[mi], bfr[ni], acc[mi][ni], 0, 0, 0);
        }
    }

    // ---- epilogue: +bias, min over ni, min over co-lanes, min across wgN, tanh^2
#pragma unroll
    for (int mi = 0; mi < 4; mi++) {
#pragma unroll
        for (int r = 0; r < 4; r++) {
            float v =        acc[mi][0][r] + bias4[0];
            v = fminf(v,     acc[mi][1][r] + bias4[1]);
            v = fminf(v,     acc[mi][2][r] + bias4[2]);
            v = fminf(v,     acc[mi][3][r] + bias4[3]);
            // reduce over the 16 co held by l15 (D col dim)
            v = fminf(v, __shfl_xor(v, 1));
            v = fminf(v, __shfl_xor(v, 2));
            v = fminf(v, __shfl_xor(v, 4));
            v = fminf(v, __shfl_xor(v, 8));
            if (l15 == 0) red[wgN][wgM * 4 + mi][lg * 4 + r] = v;
        }
    }
    __syncthreads();
    if (tid < 128) {
        int prow = tid >> 4, pcol = tid & 15;
        float v = fminf(red[0][prow][pcol], red[1][prow][pcol]);
        v = tanhf(tanhf(v));
        int oh = ohb + prow, ow = owb + pcol;
        if (oh < OH && ow < OW)
            out[((size_t)b * OH + oh) * OW + ow] = v;
    }
}

extern "C" void kernel_launch(void* const* d_in, const int* in_sizes, int n_in,
                              void* d_out, int out_size, void* d_ws, size_t ws_size,
                              hipStream_t stream) {
    const float* x    = (const float*)d_in[0];
    const float* w    = (const float*)d_in[1];
    const float* bias = (const float*)d_in[2];
    float* out = (float*)d_out;

    bf16_t* wpk = nullptr;
    if (ws_size >= (size_t)(9 * COUT * CIN * 2)) {
        wpk = (bf16_t*)d_ws;
        prepack_w<<<288, 256, 0, stream>>>(w, wpk);
    }
    dim3 grid(14, 28, 16);   // 14 ow-tiles x 28 oh-tiles x 16 batch
    conv_min_tanh<<<grid, 256, 0, stream>>>(x, w, bias, wpk, out);
}